// Round 5
// baseline (39.618 us; speedup 1.0000x reference)
//
#include <hip/hip_runtime.h>

// BPR sequence loss. B=32, L=200, K=100, D=64, V=1e6.
// R1: same-address f64 atomics were the 176us bottleneck -> per-block partials (46us).
// R3: 8 gathers in flight/wave, DPP allsum, one transcendental pass/group (33us).
// R4: barrier-free + 1024-wide reduce -> 34.9us (slight regression; reduce reverted).
// R5: test occupancy hypothesis: __launch_bounds__(256,8) forces VGPR<=64 ->
//     8 waves/SIMD (vs suspected 4), doubling in-flight gather bytes/CU.
//     If no change, we're at the random-gather fabric ceiling (~6-7 TB/s).

constexpr int B = 32;
constexpr int L = 200;
constexpr int K = 100;
constexpr int D = 64;
constexpr int BL = B * L;

// DPP row_ror:n add — rotate within 16-lane row, single VALU instruction.
template<int CTRL>
__device__ __forceinline__ float dpp_add(float v) {
    int r = __builtin_amdgcn_update_dpp(0, __builtin_bit_cast(int, v), CTRL, 0xF, 0xF, true);
    return v + __builtin_bit_cast(float, r);
}
// After this, EVERY lane of the 16-lane group holds the group sum.
__device__ __forceinline__ float group16_allsum(float v) {
    v = dpp_add<0x121>(v);  // row_ror:1
    v = dpp_add<0x122>(v);  // row_ror:2
    v = dpp_add<0x124>(v);  // row_ror:4
    v = dpp_add<0x128>(v);  // row_ror:8
    return v;
}

__device__ __forceinline__ float dot4(float4 a, float4 b) {
    return a.x * b.x + a.y * b.y + a.z * b.z + a.w * b.w;
}

__global__ __launch_bounds__(256, 8) void bpr_loss_kernel(
    const float* __restrict__ seq,     // [B*L, D]
    const float* __restrict__ table,   // [V, D]
    const float* __restrict__ mask,    // [B*L]
    const int*   __restrict__ target,  // [B*L]
    const int*   __restrict__ neg,     // [B*L, K]
    float*       __restrict__ partial) // [B*L*4] per-wave masked partials
{
    const int bl     = blockIdx.x;
    const int tid    = threadIdx.x;    // 256 threads = 16 groups x 16 lanes
    const int lane16 = tid & 15;
    const int group  = tid >> 4;
    const int wave   = tid >> 6;

    const float4 sv = *reinterpret_cast<const float4*>(seq + (size_t)bl * D + lane16 * 4);

    // Indices: pos + up to 7 negs for this group (k = group + 16*j).
    const int  base = bl * K + group;
    const int  pidx = target[bl];
    const bool has7 = (group < 4);     // k = group+96 < 100 only for groups 0..3
    int nidx[7];
    #pragma unroll
    for (int j = 0; j < 6; ++j) nidx[j] = neg[base + 16 * j];
    nidx[6] = has7 ? neg[base + 96] : 0;

    // Issue all 8 gathers back-to-back (32 VGPRs of payload in flight).
    // pos/seq rows coalesce across the wave's 4 groups (same cache lines).
    const int doff = lane16 * 4;
    float4 pv = *reinterpret_cast<const float4*>(table + (size_t)pidx * D + doff);
    float4 nv[7];
    #pragma unroll
    for (int j = 0; j < 7; ++j)
        nv[j] = *reinterpret_cast<const float4*>(table + (size_t)nidx[j] * D + doff);

    // Dot fragments + group-wide allsum (broadcasts result to all 16 lanes).
    float dp = group16_allsum(dot4(sv, pv));
    float dn[7];
    #pragma unroll
    for (int j = 0; j < 7; ++j) dn[j] = group16_allsum(dot4(sv, nv[j]));

    // Lane j (j<7) computes the loss for neg j — one transcendental pass per group.
    const int j = lane16;
    float b0 = (j & 1) ? dn[1] : dn[0];
    float b1 = (j & 1) ? dn[3] : dn[2];
    float b2 = (j & 1) ? dn[5] : dn[4];
    float b3 = dn[6];
    float c0 = (j & 2) ? b1 : b0;
    float c1 = (j & 2) ? b3 : b2;
    float dneg = (j & 4) ? c1 : c0;

    const bool valid = (j < 6) | ((j == 6) & has7);
    // -log(sigmoid(x)+eps) = log(1+t) - log(1+eps*(1+t)),  t = e^{-x}
    const float x = dp - dneg;
    const float t = __expf(fminf(-x, 80.0f));
    const float u = 1.0f + t;
    float lss = __logf(u) - __logf(fmaf(1e-8f, u, 1.0f));
    lss = valid ? lss : 0.0f;

    // group sum (all lanes) -> wave sum; no block barrier, per-wave partial.
    lss = group16_allsum(lss);
    lss += __shfl_xor(lss, 16, 64);
    lss += __shfl_xor(lss, 32, 64);

    if ((tid & 63) == 0)
        partial[bl * 4 + wave] = lss * mask[bl];
}

// Single-block reduction: 25600 partials + 6400 mask values -> final scalar.
__global__ __launch_bounds__(256) void reduce_kernel(
    const float* __restrict__ partial,  // [BL*4]
    const float* __restrict__ mask,     // [BL]
    float*       __restrict__ out)
{
    const int tid = threadIdx.x;
    const float4* p4 = reinterpret_cast<const float4*>(partial);  // BL float4s
    const float4* m4 = reinterpret_cast<const float4*>(mask);     // BL/4 float4s
    float lsum = 0.0f, msum = 0.0f;
    for (int i = tid; i < BL; i += 256) {
        float4 a = p4[i];
        lsum += (a.x + a.y) + (a.z + a.w);
    }
    for (int i = tid; i < BL / 4; i += 256) {
        float4 b = m4[i];
        msum += (b.x + b.y) + (b.z + b.w);
    }
    #pragma unroll
    for (int off = 1; off < 64; off <<= 1) {
        lsum += __shfl_xor(lsum, off, 64);
        msum += __shfl_xor(msum, off, 64);
    }
    __shared__ float s_l[4], s_m[4];
    const int wave = tid >> 6;
    if ((tid & 63) == 0) { s_l[wave] = lsum; s_m[wave] = msum; }
    __syncthreads();
    if (tid == 0) {
        float tl = s_l[0] + s_l[1] + s_l[2] + s_l[3];
        float tm = s_m[0] + s_m[1] + s_m[2] + s_m[3];
        const float denom = tm * (float)K;
        out[0] = (denom != 0.0f) ? tl / denom : 0.0f;
    }
}

extern "C" void kernel_launch(void* const* d_in, const int* in_sizes, int n_in,
                              void* d_out, int out_size, void* d_ws, size_t ws_size,
                              hipStream_t stream) {
    const float* seq    = (const float*)d_in[0];
    const float* table  = (const float*)d_in[1];
    const float* mask   = (const float*)d_in[2];
    const int*   target = (const int*)d_in[3];
    const int*   neg    = (const int*)d_in[4];
    float* partial = (float*)d_ws;   // BL*4 floats (100KB)

    bpr_loss_kernel<<<BL, 256, 0, stream>>>(seq, table, mask, target, neg, partial);
    reduce_kernel<<<1, 256, 0, stream>>>(partial, mask, (float*)d_out);
}

// Round 6
// 33.938 us; speedup vs baseline: 1.1673x; 1.1673x over previous
//
#include <hip/hip_runtime.h>

// BPR sequence loss. B=32, L=200, K=100, D=64, V=1e6.
// R1: same-address f64 atomics were the 176us bottleneck -> per-block partials (46us).
// R3: 8 gathers in flight/wave, DPP allsum, one transcendental pass/group (33.2us). BEST.
// R4: barrier-free partials + 1024-wide reduce -> 34.9us (regression, reverted).
// R5: __launch_bounds__(256,8) VGPR cap -> 39.6us (spills; occupancy was not the
//     constraint, reverted).
// R6: exact R3 restore. Roofline arithmetic: ~170MB mandatory fabric bytes /
//     256 CU / ~10 B/cyc/CU (stream-equivalent rate, = fill-kernel 7 TB/s)
//     ~= 28us main + ~5us reduce/launch tail -> 33us is the floor.

constexpr int B = 32;
constexpr int L = 200;
constexpr int K = 100;
constexpr int D = 64;
constexpr int BL = B * L;

// DPP row_ror:n add — rotate within 16-lane row, single VALU instruction.
template<int CTRL>
__device__ __forceinline__ float dpp_add(float v) {
    int r = __builtin_amdgcn_update_dpp(0, __builtin_bit_cast(int, v), CTRL, 0xF, 0xF, true);
    return v + __builtin_bit_cast(float, r);
}
// After this, EVERY lane of the 16-lane group holds the group sum.
__device__ __forceinline__ float group16_allsum(float v) {
    v = dpp_add<0x121>(v);  // row_ror:1
    v = dpp_add<0x122>(v);  // row_ror:2
    v = dpp_add<0x124>(v);  // row_ror:4
    v = dpp_add<0x128>(v);  // row_ror:8
    return v;
}

__device__ __forceinline__ float dot4(float4 a, float4 b) {
    return a.x * b.x + a.y * b.y + a.z * b.z + a.w * b.w;
}

__global__ __launch_bounds__(256) void bpr_loss_kernel(
    const float* __restrict__ seq,     // [B*L, D]
    const float* __restrict__ table,   // [V, D]
    const float* __restrict__ mask,    // [B*L]
    const int*   __restrict__ target,  // [B*L]
    const int*   __restrict__ neg,     // [B*L, K]
    float*       __restrict__ partial) // [B*L]
{
    const int bl     = blockIdx.x;
    const int tid    = threadIdx.x;    // 256 threads = 16 groups x 16 lanes
    const int lane16 = tid & 15;
    const int group  = tid >> 4;

    const float4 sv = *reinterpret_cast<const float4*>(seq + (size_t)bl * D + lane16 * 4);

    // Indices: pos + up to 7 negs for this group (k = group + 16*j).
    const int  base = bl * K + group;
    const int  pidx = target[bl];
    const bool has7 = (group < 4);     // k = group+96 < 100 only for groups 0..3
    int nidx[7];
    #pragma unroll
    for (int j = 0; j < 6; ++j) nidx[j] = neg[base + 16 * j];
    nidx[6] = has7 ? neg[base + 96] : 0;

    // Issue all 8 gathers back-to-back (32 VGPRs of payload in flight).
    // pos/seq rows coalesce across the wave's 4 groups (same cache lines).
    const int doff = lane16 * 4;
    float4 pv = *reinterpret_cast<const float4*>(table + (size_t)pidx * D + doff);
    float4 nv[7];
    #pragma unroll
    for (int j = 0; j < 7; ++j)
        nv[j] = *reinterpret_cast<const float4*>(table + (size_t)nidx[j] * D + doff);

    // Dot fragments + group-wide allsum (broadcasts result to all 16 lanes).
    float dp = group16_allsum(dot4(sv, pv));
    float dn[7];
    #pragma unroll
    for (int j = 0; j < 7; ++j) dn[j] = group16_allsum(dot4(sv, nv[j]));

    // Lane j (j<7) computes the loss for neg j — one transcendental pass per group.
    const int j = lane16;
    float b0 = (j & 1) ? dn[1] : dn[0];
    float b1 = (j & 1) ? dn[3] : dn[2];
    float b2 = (j & 1) ? dn[5] : dn[4];
    float b3 = dn[6];
    float c0 = (j & 2) ? b1 : b0;
    float c1 = (j & 2) ? b3 : b2;
    float dneg = (j & 4) ? c1 : c0;

    const bool valid = (j < 6) | ((j == 6) & has7);
    // -log(sigmoid(x)+eps) = log(1+t) - log(1+eps*(1+t)),  t = e^{-x}
    // clamp exponent so t stays finite (result saturates at -log(eps)=18.42, as ref does)
    const float x = dp - dneg;
    const float t = __expf(fminf(-x, 80.0f));
    const float u = 1.0f + t;
    float lss = __logf(u) - __logf(fmaf(1e-8f, u, 1.0f));
    lss = valid ? lss : 0.0f;

    // group sum -> wave sum -> block sum
    lss = group16_allsum(lss);
    lss += __shfl_xor(lss, 16, 64);
    lss += __shfl_xor(lss, 32, 64);

    __shared__ float s_wave[4];
    if ((tid & 63) == 0) s_wave[tid >> 6] = lss;
    __syncthreads();
    if (tid == 0)
        partial[bl] = (s_wave[0] + s_wave[1] + s_wave[2] + s_wave[3]) * mask[bl];
}

__global__ __launch_bounds__(256) void reduce_kernel(
    const float* __restrict__ partial,  // [BL]
    const float* __restrict__ mask,     // [BL]
    float*       __restrict__ out)
{
    const int tid = threadIdx.x;
    const float4* p4 = reinterpret_cast<const float4*>(partial);
    const float4* m4 = reinterpret_cast<const float4*>(mask);
    float lsum = 0.0f, msum = 0.0f;
    for (int i = tid; i < BL / 4; i += 256) {
        float4 a = p4[i];
        float4 b = m4[i];
        lsum += (a.x + a.y) + (a.z + a.w);
        msum += (b.x + b.y) + (b.z + b.w);
    }
    #pragma unroll
    for (int off = 1; off < 64; off <<= 1) {
        lsum += __shfl_xor(lsum, off, 64);
        msum += __shfl_xor(msum, off, 64);
    }
    __shared__ float s_l[4], s_m[4];
    const int wave = tid >> 6;
    if ((tid & 63) == 0) { s_l[wave] = lsum; s_m[wave] = msum; }
    __syncthreads();
    if (tid == 0) {
        float tl = s_l[0] + s_l[1] + s_l[2] + s_l[3];
        float tm = s_m[0] + s_m[1] + s_m[2] + s_m[3];
        const float denom = tm * (float)K;
        out[0] = (denom != 0.0f) ? tl / denom : 0.0f;
    }
}

extern "C" void kernel_launch(void* const* d_in, const int* in_sizes, int n_in,
                              void* d_out, int out_size, void* d_ws, size_t ws_size,
                              hipStream_t stream) {
    const float* seq    = (const float*)d_in[0];
    const float* table  = (const float*)d_in[1];
    const float* mask   = (const float*)d_in[2];
    const int*   target = (const int*)d_in[3];
    const int*   neg    = (const int*)d_in[4];
    float* partial = (float*)d_ws;   // BL floats

    bpr_loss_kernel<<<BL, 256, 0, stream>>>(seq, table, mask, target, neg, partial);
    reduce_kernel<<<1, 256, 0, stream>>>(partial, mask, (float*)d_out);
}